// Round 15
// baseline (228.745 us; speedup 1.0000x reference)
//
#include <hip/hip_runtime.h>
#include <hip/hip_bf16.h>

// ScaledDotProductAttention: B=2 H=16 S=2048 DK=64, fp32 in, outputs
// (attn_out [B,H,S,DK], weights [B,H,S,S]) concatenated in d_out (fp32).
//
// R15: ZERO-BARRIER kernel via FRAGMENT-ORDERED K/V images. pack_kv writes
// img[tile][slot(kk,ct)][lane] = the exact 16B bf16 fragment lane l needs
// for that MFMA slot -> waves load operands with coalesced dwordx4 (1KB/
// instr, L2-resident) straight into registers. No K/V LDS, no cross-wave
// barriers at all (R14 null + all-pipes-idle profile -> chain/barrier
// serialization was the residual). LDS = 2KB wave-local Ps (cross-lane P
// redistribution + W transposed flush; lgkm fence only). Single-wave
// blocks (64thr, grid 4096). Keeps: swapped QK^T, fixed m=0, bit mask,
// bf16-W from Ps, transposed full-256B-segment NT W stores, NT O stores.

namespace {

constexpr int Bc = 2, Hc = 16, Sc = 2048, Dc = 64;
constexpr int KT = 64;             // kv cols per tile
constexpr int NKV = Sc / KT;       // 32
constexpr int NQW = Sc / 16;       // 128 q-groups of 16 rows per bh
constexpr int NBH = Bc * Hc;       // 32
constexpr float SCALE2 = 0.125f * 1.44269504088896340736f; // (1/sqrt(64))*log2(e)

// workspace layout
constexpr size_t BITS_BYTES = (size_t)Sc * Sc / 8;            // 512 KB
constexpr size_t IMG_BYTES  = (size_t)NBH * NKV * 8192;       // 8 MB each
constexpr size_t KIMG_OFF   = BITS_BYTES;
constexpr size_t VIMG_OFF   = BITS_BYTES + IMG_BYTES;
constexpr size_t WS_FULL    = BITS_BYTES + 2 * IMG_BYTES;     // ~17 MB

using short8 = __attribute__((ext_vector_type(8))) short;  // 8 bf16 (4 VGPR)
using f32x4  = __attribute__((ext_vector_type(4))) float;  // MFMA acc / stores
using u32x4  = __attribute__((ext_vector_type(4))) unsigned; // 16B copies

// XOR swizzle for 64-col bf16 rows (128B stride, 16 rows = 2KB slice).
__device__ __forceinline__ int swz(int row, int bytecol) {
    return row * 128 + (bytecol ^ ((row & 7) << 4));
}

// 2x f32 -> packed bf16 (RNE) in ONE VALU instr (gfx950; no builtin, T12)
__device__ __forceinline__ unsigned cvtpk(float a, float b) {
    unsigned r;
    asm("v_cvt_pk_bf16_f32 %0, %1, %2" : "=v"(r) : "v"(a), "v"(b));
    return r;
}

__device__ __forceinline__ f32x4 mfma16(short8 a, short8 b, f32x4 c) {
    return __builtin_amdgcn_mfma_f32_16x16x32_bf16(a, b, c, 0, 0, 0);
}

// wave-local LDS fence: order ds_write -> ds_read within this wave
__device__ __forceinline__ void fence_lgkm() {
    __builtin_amdgcn_sched_barrier(0);
    asm volatile("s_waitcnt lgkmcnt(0)" ::: "memory");
    __builtin_amdgcn_sched_barrier(0);
}

__device__ __forceinline__ short8 pack8(float4 a, float4 b) {
    u32x4 pk = { cvtpk(a.x, a.y), cvtpk(a.z, a.w),
                 cvtpk(b.x, b.y), cvtpk(b.z, b.w) };
    union { u32x4 u; short8 s; } c; c.u = pk; return c.s;
}

// ---- pre-kernels ----
__global__ __launch_bounds__(256) void pack_mask(
    const int* __restrict__ Mg, unsigned long long* __restrict__ bits)
{
    int tg = blockIdx.x * 256 + threadIdx.x;        // over S*S
    int v = Mg[tg];
    unsigned long long b = __ballot(v != 0);
    if ((threadIdx.x & 63) == 0) bits[tg >> 6] = b;
}

// one block per (bh, kv): emit FRAGMENT-ORDERED 8KB images.
// kimg fragment f = s*64+l, s=(kk*4+ct): K[ct*16+l15][kk*32+hi4*8 .. +8]
// vimg fragment f = s*64+l, s=(kk*4+dt): V^T[dt*16+l15][kk*32+hi4*8 .. +8]
//                                      = V[kk*32+hi4*8+e][dt*16+l15]
__global__ __launch_bounds__(256) void pack_kv(
    const float* __restrict__ Kg, const float* __restrict__ Vg,
    char* __restrict__ kimg, char* __restrict__ vimg)
{
    const int b = blockIdx.x;                   // 0..1023
    const int bh = b >> 5, kv = b & 31;
    const int t = threadIdx.x;
    const size_t off = (size_t)bh * Sc * Dc + (size_t)kv * KT * Dc;
    #pragma unroll
    for (int i = 0; i < 2; ++i) {
        int f = t + 256 * i;                    // 0..511
        int s = f >> 6, l = f & 63;
        int l15 = l & 15, hi4 = l >> 4;
        int kk = s >> 2, q = s & 3;             // q = ct (K) / dt (V)
        {   // K fragment: row-major read
            const float* kp = Kg + off + (size_t)(q * 16 + l15) * Dc
                              + kk * 32 + hi4 * 8;
            float4 a = *reinterpret_cast<const float4*>(kp);
            float4 c = *reinterpret_cast<const float4*>(kp + 4);
            u32x4 pk = { cvtpk(a.x, a.y), cvtpk(a.z, a.w),
                         cvtpk(c.x, c.y), cvtpk(c.z, c.w) };
            *reinterpret_cast<u32x4*>(kimg + (size_t)b * 8192 + f * 16) = pk;
        }
        {   // V fragment: column gather (16-lane groups still hit 64B lines)
            const float* vp = Vg + off + (size_t)(kk * 32 + hi4 * 8) * Dc
                              + q * 16 + l15;
            float v0 = vp[0 * Dc], v1 = vp[1 * Dc], v2 = vp[2 * Dc],
                  v3 = vp[3 * Dc], v4 = vp[4 * Dc], v5 = vp[5 * Dc],
                  v6 = vp[6 * Dc], v7 = vp[7 * Dc];
            u32x4 pk = { cvtpk(v0, v1), cvtpk(v2, v3),
                         cvtpk(v4, v5), cvtpk(v6, v7) };
            *reinterpret_cast<u32x4*>(vimg + (size_t)b * 8192 + f * 16) = pk;
        }
    }
}

// MODE: 2 = fragment images + bit mask; 0 = direct-global gather + raw mask
template <int MODE>
__global__ __launch_bounds__(64, 4)
void attn_main(const float* __restrict__ Qg, const float* __restrict__ Kg,
               const float* __restrict__ Vg, const int* __restrict__ Mg,
               const unsigned* __restrict__ mbits,
               const char* __restrict__ kimg, const char* __restrict__ vimg,
               float* __restrict__ Og, float* __restrict__ Wg)
{
    __shared__ char lds_s[2048];                // wave-local Ps [16][64] bf16
    char* lds = lds_s;

    // XCD-grouped mapping: 4 bh per XCD -> images stay L2-resident.
    const int bid = blockIdx.x;                 // 0..4095
    const int xcd = bid & 7, idx = bid >> 3;    // idx 0..511
    const int bh  = xcd * 4 + (idx & 3);        // 0..31
    const int q16 = idx >> 2;                   // 0..127 (16-row q group)

    const int lane = threadIdx.x;               // 0..63 (single wave)
    const int l15  = lane & 15, hi4 = lane >> 4;

    const size_t bh_off = (size_t)bh * Sc * Dc;
    const int qg0 = q16 * 16 + l15;             // this lane's q row
    float* Ob = Og + bh_off + (size_t)q16 * 16 * Dc;
    float* Wb = Wg + (size_t)bh * Sc * Sc + (size_t)q16 * 16 * Sc;
    const float* Kb = Kg + bh_off;
    const float* Vb = Vg + bh_off;
    const char* kbase = kimg + (size_t)(bh * 32) * 8192;
    const char* vbase = vimg + (size_t)(bh * 32) * 8192;

    // ---- Q fragments straight from global (once) ----
    short8 qf[2];
    #pragma unroll
    for (int kk = 0; kk < 2; ++kk) {
        const float* qp = Qg + bh_off + (size_t)qg0 * Dc + kk * 32 + hi4 * 8;
        float4 a = *reinterpret_cast<const float4*>(qp);
        float4 b = *reinterpret_cast<const float4*>(qp + 4);
        a.x *= SCALE2; a.y *= SCALE2; a.z *= SCALE2; a.w *= SCALE2;
        b.x *= SCALE2; b.y *= SCALE2; b.z *= SCALE2; b.w *= SCALE2;
        qf[kk] = pack8(a, b);
    }

    // ================= pass 1: row sums only (fixed m = 0) =================
    float lsum = 0.f;
    #pragma unroll 2
    for (int kv = 0; kv < NKV; ++kv) {
        short8 kf[8];
        if constexpr (MODE == 2) {
            const char* kb = kbase + (size_t)kv * 8192 + lane * 16;
            #pragma unroll
            for (int s = 0; s < 8; ++s)
                kf[s] = *reinterpret_cast<const short8*>(kb + s * 1024);
        } else {
            #pragma unroll
            for (int s = 0; s < 8; ++s) {
                int kk = s >> 2, ct = s & 3;
                const float* kp = Kb + (size_t)(kv * KT + ct * 16 + l15) * Dc
                                  + kk * 32 + hi4 * 8;
                kf[s] = pack8(*reinterpret_cast<const float4*>(kp),
                              *reinterpret_cast<const float4*>(kp + 4));
            }
        }

        uint2 mb0;
        if constexpr (MODE == 2)
            mb0 = *reinterpret_cast<const uint2*>(
                mbits + (size_t)qg0 * 64 + kv * 2);

        f32x4 sc[4];
        #pragma unroll
        for (int ct = 0; ct < 4; ++ct) sc[ct] = f32x4{0.f, 0.f, 0.f, 0.f};
        #pragma unroll
        for (int kk = 0; kk < 2; ++kk)
            #pragma unroll
            for (int ct = 0; ct < 4; ++ct)
                sc[ct] = mfma16(kf[kk * 4 + ct], qf[kk], sc[ct]);

        float acc = 0.f;
        #pragma unroll
        for (int ct = 0; ct < 4; ++ct) {
            unsigned word = 0;
            if constexpr (MODE == 2) word = (ct >= 2) ? mb0.y : mb0.x;
            #pragma unroll
            for (int r = 0; r < 4; ++r) {
                bool keep;
                if constexpr (MODE == 2)
                    keep = (word >> ((ct & 1) * 16 + hi4 * 4 + r)) & 1;
                else
                    keep = Mg[(size_t)qg0 * Sc + kv * KT + ct * 16
                              + hi4 * 4 + r] != 0;
                acc += keep ? exp2f(sc[ct][r]) : 0.0f;
            }
        }
        lsum += acc;
    }

    // cross-lane merge over the 4 hi4 groups (each holds a k-quarter)
    float rls;
    {
        float s = lsum;
        s += __shfl_xor(s, 16);
        s += __shfl_xor(s, 32);
        rls = 1.0f / s;
    }

    // ================= pass 2: W write (via Ps, transposed) + PV ===========
    f32x4 oa[4];
    #pragma unroll
    for (int dt = 0; dt < 4; ++dt) oa[dt] = f32x4{0.f, 0.f, 0.f, 0.f};

    for (int kv = 0; kv < NKV; ++kv) {
        // QK^T operands from fragment image (coalesced) or direct gather
        short8 kf[8];
        if constexpr (MODE == 2) {
            const char* kb = kbase + (size_t)kv * 8192 + lane * 16;
            #pragma unroll
            for (int s = 0; s < 8; ++s)
                kf[s] = *reinterpret_cast<const short8*>(kb + s * 1024);
        } else {
            #pragma unroll
            for (int s = 0; s < 8; ++s) {
                int kk = s >> 2, ct = s & 3;
                const float* kp = Kb + (size_t)(kv * KT + ct * 16 + l15) * Dc
                                  + kk * 32 + hi4 * 8;
                kf[s] = pack8(*reinterpret_cast<const float4*>(kp),
                              *reinterpret_cast<const float4*>(kp + 4));
            }
        }

        uint2 mb0;
        if constexpr (MODE == 2)
            mb0 = *reinterpret_cast<const uint2*>(
                mbits + (size_t)qg0 * 64 + kv * 2);

        f32x4 sc[4];
        #pragma unroll
        for (int ct = 0; ct < 4; ++ct) sc[ct] = f32x4{0.f, 0.f, 0.f, 0.f};
        #pragma unroll
        for (int kk = 0; kk < 2; ++kk)
            #pragma unroll
            for (int ct = 0; ct < 4; ++ct)
                sc[ct] = mfma16(kf[kk * 4 + ct], qf[kk], sc[ct]);

        // weights -> Ps (bf16; serves PV A-operand AND transposed W flush)
        #pragma unroll
        for (int ct = 0; ct < 4; ++ct) {
            unsigned word = 0;
            if constexpr (MODE == 2) word = (ct >= 2) ? mb0.y : mb0.x;
            float p[4];
            #pragma unroll
            for (int r = 0; r < 4; ++r) {
                bool keep;
                if constexpr (MODE == 2)
                    keep = (word >> ((ct & 1) * 16 + hi4 * 4 + r)) & 1;
                else
                    keep = Mg[(size_t)qg0 * Sc + kv * KT + ct * 16
                              + hi4 * 4 + r] != 0;
                p[r] = keep ? exp2f(sc[ct][r]) * rls : 0.0f;
            }
            uint2 pp; pp.x = cvtpk(p[0], p[1]); pp.y = cvtpk(p[2], p[3]);
            *reinterpret_cast<uint2*>(
                lds + swz(l15, ct * 32 + hi4 * 8)) = pp;
        }
        fence_lgkm();   // wave-local: Ps writes -> reads below

        // PV: V fragments from image (coalesced) or direct column gather
        short8 vf[8];
        if constexpr (MODE == 2) {
            const char* vb = vbase + (size_t)kv * 8192 + lane * 16;
            #pragma unroll
            for (int s = 0; s < 8; ++s)
                vf[s] = *reinterpret_cast<const short8*>(vb + s * 1024);
        } else {
            #pragma unroll
            for (int s = 0; s < 8; ++s) {
                int kk = s >> 2, dt = s & 3;
                const float* vp = Vb + (size_t)(kv * KT + kk * 32 + hi4 * 8) * Dc
                                  + dt * 16 + l15;
                u32x4 pk = { cvtpk(vp[0 * Dc], vp[1 * Dc]),
                             cvtpk(vp[2 * Dc], vp[3 * Dc]),
                             cvtpk(vp[4 * Dc], vp[5 * Dc]),
                             cvtpk(vp[6 * Dc], vp[7 * Dc]) };
                union { u32x4 u; short8 s8; } c; c.u = pk; vf[s] = c.s8;
            }
        }
        #pragma unroll
        for (int kk = 0; kk < 2; ++kk) {
            int bc = kk * 64 + hi4 * 16;
            short8 a0 = *reinterpret_cast<const short8*>(lds + swz(l15, bc));
            #pragma unroll
            for (int dt = 0; dt < 4; ++dt)
                oa[dt] = mfma16(a0, vf[kk * 4 + dt], oa[dt]);
        }

        // W flush, transposed, read from Ps: lane -> local row j*4 + hi4,
        // k = l15*4..+3. Each store = 4 FULL 256B line-aligned row segments,
        // NONTEMPORAL (R10+R12 wins).
        #pragma unroll
        for (int j = 0; j < 4; ++j) {
            int row = j * 4 + hi4;
            uint2 pw = *reinterpret_cast<const uint2*>(
                lds + swz(row, l15 * 8));
            f32x4 wv;
            wv[0] = __uint_as_float(pw.x << 16);
            wv[1] = __uint_as_float(pw.x & 0xffff0000u);
            wv[2] = __uint_as_float(pw.y << 16);
            wv[3] = __uint_as_float(pw.y & 0xffff0000u);
            __builtin_nontemporal_store(
                wv, reinterpret_cast<f32x4*>(
                    Wb + (size_t)row * Sc + kv * KT + l15 * 4));
        }
    }

    // epilogue: store O (nontemporal, coalesced)
    #pragma unroll
    for (int dt = 0; dt < 4; ++dt)
        #pragma unroll
        for (int r = 0; r < 4; ++r) {
            int ql = hi4 * 4 + r;
            __builtin_nontemporal_store(
                oa[dt][r], Ob + (size_t)ql * Dc + dt * 16 + l15);
        }
}

} // namespace

extern "C" void kernel_launch(void* const* d_in, const int* in_sizes, int n_in,
                              void* d_out, int out_size, void* d_ws, size_t ws_size,
                              hipStream_t stream) {
    const float* Qg = (const float*)d_in[0];
    const float* Kg = (const float*)d_in[1];
    const float* Vg = (const float*)d_in[2];
    const int*   Mg = (const int*)d_in[3];
    float* out_o = (float*)d_out;
    float* out_w = out_o + (size_t)Bc * Hc * Sc * Dc;   // weights after output

    char* ws = (char*)d_ws;
    dim3 grid(NBH * NQW / 4 * 4), blk(64);   // 32 bh * 128 qgroups = 4096

    if (d_ws != nullptr && ws_size >= WS_FULL) {
        unsigned long long* bits = (unsigned long long*)ws;
        char* kimg = ws + KIMG_OFF;
        char* vimg = ws + VIMG_OFF;
        pack_mask<<<(Sc * Sc) / 256, 256, 0, stream>>>(Mg, bits);
        pack_kv<<<NBH * NKV, 256, 0, stream>>>(Kg, Vg, kimg, vimg);
        attn_main<2><<<4096, blk, 0, stream>>>(
            Qg, Kg, Vg, Mg, (const unsigned*)bits, kimg, vimg, out_o, out_w);
    } else {
        attn_main<0><<<4096, blk, 0, stream>>>(
            Qg, Kg, Vg, Mg, nullptr, nullptr, nullptr, out_o, out_w);
    }
}